// Round 1
// baseline (635.211 us; speedup 1.0000x reference)
//
#include <hip/hip_runtime.h>
#include <hip/hip_fp16.h>

// LightGCN propagation on MI355X — round 4: kill fill's write amplification.
// N = 100000 nodes, D = 128, E = 2,000,000 edges, 3 layers.
//
// Round-3 counters: lgcn_fill = 159 us, WRITE_SIZE 124 MB for a 16 MB payload
// (8x line amplification from random 8 B scatters) at only 11% HBM peak.
// Round 4 replaces the single random scatter with a two-phase counting sort:
//   - lgcn_bucket: scatter edges into 64-row bucket regions of a staging
//     buffer (consecutive positions per bucket -> line-coalesced writes).
//     Row-within-bucket (6 bits) packed above the 17-bit col in one int.
//     Bucket cursors padded 1/cacheline to avoid same-line atomic serialize.
//   - lgcn_place: one block per bucket; sequential staging read, scatter
//     confined to a ~10 KB window handled by ONE block/XCD -> L2-merged.
// Staging reuses bufB (x1 buffer is dead until spmm layer 1).
//
// ws layout (256 B aligned slices):
//   bufA : nd fp16 (x0, later reused for x2)     25.6 MB
//   bufB : nd fp16 (x1; staging int2 during build) 25.6 MB
//   edges: E int2                                 16 MB
//   counts, row_ptr(+1), cursor, bsums, bcursor   ~1.3 MB

#define DIM 128

static inline size_t align_up(size_t v, size_t a) { return (v + a - 1) & ~(a - 1); }

__global__ void lgcn_conv(const float2* __restrict__ emb, __half2* __restrict__ x0,
                          int n2) {
    int i = blockIdx.x * blockDim.x + threadIdx.x;
    if (i < n2) x0[i] = __float22half2_rn(emb[i]);
}

__global__ void lgcn_hist(const int* __restrict__ rows, int* __restrict__ counts,
                          int nedges) {
    int e = blockIdx.x * blockDim.x + threadIdx.x;
    if (e < nedges) atomicAdd(&counts[rows[e]], 1);
}

// Level-1 scan: each 256-thread block scans 1024 counts (4/thread).
// Writes per-element block-local exclusive prefix into row_ptr[i],
// block total into bsums[blk].
__global__ void __launch_bounds__(256)
lgcn_scan1(const int* __restrict__ counts, int* __restrict__ row_ptr,
           int* __restrict__ bsums, int n) {
    __shared__ int wsum[4];
    const int tid  = threadIdx.x;
    const int lane = tid & 63;
    const int wid  = tid >> 6;
    const int i0   = blockIdx.x * 1024 + tid * 4;

    int c0 = 0, c1 = 0, c2 = 0, c3 = 0;
    if (i0 + 3 < n) {
        int4 c = *(const int4*)(counts + i0);
        c0 = c.x; c1 = c.y; c2 = c.z; c3 = c.w;
    } else {
        if (i0 + 0 < n) c0 = counts[i0 + 0];
        if (i0 + 1 < n) c1 = counts[i0 + 1];
        if (i0 + 2 < n) c2 = counts[i0 + 2];
        if (i0 + 3 < n) c3 = counts[i0 + 3];
    }
    const int t1 = c0 + c1, t2 = t1 + c2, tsum = t2 + c3;

    // wave inclusive scan of per-thread sums
    int incl = tsum;
    #pragma unroll
    for (int off = 1; off < 64; off <<= 1) {
        int t = __shfl_up(incl, off, 64);
        if (lane >= off) incl += t;
    }
    if (lane == 63) wsum[wid] = incl;
    __syncthreads();
    int woff = 0;
    #pragma unroll
    for (int w = 0; w < 4; ++w) woff += (w < wid) ? wsum[w] : 0;

    const int ex = woff + incl - tsum;  // exclusive prefix of this thread's chunk
    if (i0 + 0 < n) row_ptr[i0 + 0] = ex;
    if (i0 + 1 < n) row_ptr[i0 + 1] = ex + c0;
    if (i0 + 2 < n) row_ptr[i0 + 2] = ex + t1;
    if (i0 + 3 < n) row_ptr[i0 + 3] = ex + t2;
    if (tid == 255) bsums[blockIdx.x] = woff + incl;
}

// Level-2: exclusive-scan the (<=128) block sums in one block; write total.
__global__ void __launch_bounds__(128)
lgcn_scan2(int* __restrict__ bsums, int* __restrict__ row_ptr, int nb, int n) {
    __shared__ int w0s;
    const int tid  = threadIdx.x;
    const int lane = tid & 63;
    const int wid  = tid >> 6;
    int v = (tid < nb) ? bsums[tid] : 0;
    int incl = v;
    #pragma unroll
    for (int off = 1; off < 64; off <<= 1) {
        int t = __shfl_up(incl, off, 64);
        if (lane >= off) incl += t;
    }
    if (tid == 63) w0s = incl;
    __syncthreads();
    const int ex = incl - v + ((wid == 1) ? w0s : 0);
    if (tid < nb) bsums[tid] = ex;
    if (tid == nb - 1) row_ptr[n] = ex + v;
}

// Level-3: add block bases; produce final row_ptr, fill cursors, and
// bucket cursors (one padded slot per 64-row bucket; base = row_ptr[b<<6]).
__global__ void lgcn_scan3(int* __restrict__ row_ptr, int* __restrict__ cursor,
                           const int* __restrict__ bsums, int* __restrict__ bcursor,
                           int n) {
    int i = blockIdx.x * blockDim.x + threadIdx.x;
    if (i < n) {
        int v = row_ptr[i] + bsums[i >> 10];
        row_ptr[i] = v;
        cursor[i]  = v;
        if ((i & 63) == 0) bcursor[(i >> 6) * 16] = v;  // 1 counter / 64B line
    }
}

// Phase A: scatter edges into 64-row bucket regions of staging.
// Consecutive positions within a bucket -> line-coalesced writes.
// Record: (col | rlow<<17, val_bits); col < 2^17, rlow < 64.
__global__ void lgcn_bucket(const int* __restrict__ rows, const int* __restrict__ cols,
                            const float* __restrict__ vals, int* __restrict__ bcursor,
                            int2* __restrict__ staging, int nedges) {
    int e = blockIdx.x * blockDim.x + threadIdx.x;
    if (e < nedges) {
        int r   = rows[e];
        int pos = atomicAdd(&bcursor[(r >> 6) * 16], 1);
        staging[pos] = make_int2(cols[e] | ((r & 63) << 17), __float_as_int(vals[e]));
    }
}

// Phase B: one block per bucket; sequential staging read, final scatter
// confined to this bucket's ~10 KB output window (single block -> single
// XCD -> writes merge in L2).
__global__ void __launch_bounds__(256)
lgcn_place(const int* __restrict__ row_ptr, const int2* __restrict__ staging,
           int* __restrict__ cursor, int2* __restrict__ edges, int n) {
    const int b    = blockIdx.x;
    const int rbeg = b << 6;
    const int rend = min(rbeg + 64, n);
    const int beg  = row_ptr[rbeg];
    const int end  = row_ptr[rend];
    for (int i = beg + threadIdx.x; i < end; i += blockDim.x) {
        int2 p   = staging[i];
        int row  = rbeg + ((p.x >> 17) & 63);
        int pos  = atomicAdd(&cursor[row], 1);
        edges[pos] = make_int2(p.x & 0x1FFFF, p.y);
    }
}

// One wave per row; lane j holds dims [2j, 2j+1] (one __half2 = 4 B gather/lane).
// mode 0: xout[row] = fp16(s)
// mode 1: out[row]  = (emb[row] + x1[row] + xin[row](=x2) + s) * 0.25  (fp32)
__global__ void __launch_bounds__(256)
lgcn_spmm(const int* __restrict__ row_ptr, const int2* __restrict__ edges,
          const __half2* __restrict__ xin, __half2* __restrict__ xout,
          const float2* __restrict__ emb, const __half2* __restrict__ x1h,
          float2* __restrict__ out, int n, int mode) {
    const int wave = blockIdx.x * 4 + (threadIdx.x >> 6);
    const int lane = threadIdx.x & 63;
    if (wave >= n) return;
    const int beg = row_ptr[wave];
    const int end = row_ptr[wave + 1];

    float sx = 0.f, sy = 0.f;
    int e = beg;
    for (; e + 4 <= end; e += 4) {
        int2 p0 = edges[e + 0], p1 = edges[e + 1];
        int2 p2 = edges[e + 2], p3 = edges[e + 3];
        float2 a0 = __half22float2(xin[p0.x * 64 + lane]);
        float2 a1 = __half22float2(xin[p1.x * 64 + lane]);
        float2 a2 = __half22float2(xin[p2.x * 64 + lane]);
        float2 a3 = __half22float2(xin[p3.x * 64 + lane]);
        float v0 = __int_as_float(p0.y), v1 = __int_as_float(p1.y);
        float v2 = __int_as_float(p2.y), v3 = __int_as_float(p3.y);
        sx = fmaf(v0, a0.x, sx); sy = fmaf(v0, a0.y, sy);
        sx = fmaf(v1, a1.x, sx); sy = fmaf(v1, a1.y, sy);
        sx = fmaf(v2, a2.x, sx); sy = fmaf(v2, a2.y, sy);
        sx = fmaf(v3, a3.x, sx); sy = fmaf(v3, a3.y, sy);
    }
    for (; e < end; ++e) {
        int2 p = edges[e];
        float2 a = __half22float2(xin[p.x * 64 + lane]);
        float v  = __int_as_float(p.y);
        sx = fmaf(v, a.x, sx); sy = fmaf(v, a.y, sy);
    }

    const int o = wave * 64 + lane;
    if (mode == 0) {
        xout[o] = __float22half2_rn(make_float2(sx, sy));
    } else {
        float2 em = emb[o];
        float2 b1 = __half22float2(x1h[o]);
        float2 b2 = __half22float2(xin[o]);
        out[o] = make_float2((em.x + b1.x + b2.x + sx) * 0.25f,
                             (em.y + b1.y + b2.y + sy) * 0.25f);
    }
}

extern "C" void kernel_launch(void* const* d_in, const int* in_sizes, int n_in,
                              void* d_out, int out_size, void* d_ws, size_t ws_size,
                              hipStream_t stream) {
    const float* emb  = (const float*)d_in[0];
    const int*   rows = (const int*)d_in[1];
    const int*   cols = (const int*)d_in[2];
    const float* vals = (const float*)d_in[3];

    const int  n_nodes = in_sizes[0] / DIM;    // 100000
    const int  nedges  = in_sizes[1];          // 2000000
    const long nd      = (long)n_nodes * DIM;  // 12.8M

    char* ws = (char*)d_ws;
    size_t off = 0;
    __half2* bufA = (__half2*)(ws + off); off = align_up(off + nd * 2, 256);   // x0 then x2
    __half2* bufB = (__half2*)(ws + off); off = align_up(off + nd * 2, 256);   // x1 / staging
    int2* edges   = (int2*)(ws + off);    off = align_up(off + (size_t)nedges * 8, 256);
    int* counts   = (int*)(ws + off);     off = align_up(off + (size_t)n_nodes * 4, 256);
    int* row_ptr  = (int*)(ws + off);     off = align_up(off + (size_t)(n_nodes + 1) * 4, 256);
    int* cursor   = (int*)(ws + off);     off = align_up(off + (size_t)n_nodes * 4, 256);
    int* bsums    = (int*)(ws + off);     off = align_up(off + 1024, 256);
    const int nbuck = (n_nodes + 63) >> 6;                 // 1563 buckets of 64 rows
    int* bcursor  = (int*)(ws + off);     off = align_up(off + (size_t)nbuck * 16 * 4, 256);
    float2* out   = (float2*)d_out;

    int2* staging = (int2*)bufB;  // bufB is dead until spmm layer 1

    const int BS = 256;
    const int grid_e  = (nedges + BS - 1) / BS;
    const int n2      = (int)(nd / 2);
    const int grid_c  = (n2 + BS - 1) / BS;
    const int nb      = (n_nodes + 1023) / 1024;          // 98 (<=128)
    const int grid_n  = (n_nodes + BS - 1) / BS;
    const int grid_s  = (n_nodes + 3) / 4;                // 4 rows per block

    // emb -> fp16 x0
    lgcn_conv<<<grid_c, BS, 0, stream>>>((const float2*)emb, bufA, n2);

    // CSR build
    hipMemsetAsync(counts, 0, (size_t)n_nodes * sizeof(int), stream);
    lgcn_hist<<<grid_e, BS, 0, stream>>>(rows, counts, nedges);
    lgcn_scan1<<<nb, 256, 0, stream>>>(counts, row_ptr, bsums, n_nodes);
    lgcn_scan2<<<1, 128, 0, stream>>>(bsums, row_ptr, nb, n_nodes);
    lgcn_scan3<<<grid_n, BS, 0, stream>>>(row_ptr, cursor, bsums, bcursor, n_nodes);
    lgcn_bucket<<<grid_e, BS, 0, stream>>>(rows, cols, vals, bcursor, staging, nedges);
    lgcn_place<<<nbuck, BS, 0, stream>>>(row_ptr, staging, cursor, edges, n_nodes);

    // 3 SpMM layers: x1 = A x0, x2 = A x1, out = (emb + x1 + x2 + A x2)/4
    lgcn_spmm<<<grid_s, BS, 0, stream>>>(row_ptr, edges, bufA, bufB,
                                         nullptr, nullptr, nullptr, n_nodes, 0);
    lgcn_spmm<<<grid_s, BS, 0, stream>>>(row_ptr, edges, bufB, bufA,
                                         nullptr, nullptr, nullptr, n_nodes, 0);
    lgcn_spmm<<<grid_s, BS, 0, stream>>>(row_ptr, edges, bufA, nullptr,
                                         (const float2*)emb, bufB, out, n_nodes, 1);
}

// Round 2
// 452.965 us; speedup vs baseline: 1.4023x; 1.4023x over previous
//
#include <hip/hip_runtime.h>
#include <hip/hip_fp16.h>

// LightGCN propagation on MI355X — round 5: deterministic two-pass edge sort.
// N = 100000 nodes, D = 128, E = 2,000,000 edges, 3 layers.
//
// Round-4 post-mortem: the atomic-cursor bucket scatter still had ~7x write
// amplification (113 MB for 16 MB payload). Root cause: each bucket's cursor
// advanced from all 8 XCDs concurrently, so every 64 B staging line received
// its records from ~8 non-coherent XCD L2s -> partial-line writebacks never
// merged, plus cross-XCD atomic line bouncing on 1563 hot cursors.
//
// Round 5: no global atomics anywhere in the build.
//   - lgcn_phist: 256 blocks x contiguous edge chunk; LDS hist over 512
//     coarse buckets (256 rows each); write ghist[k][b] (bucket-major).
//   - 3-level scan of the 131072-entry ghist -> gbase[k][b]: exact
//     deterministic write base per (block,bucket).
//   - lgcn_part: block b re-reads its chunk, writes each edge at
//     staging[lds_cnt[bucket]++] (LDS atomic). Each (block,bucket) range is
//     contiguous + written by ONE CU/XCD -> L2-merged; only boundary lines
//     shared (~1.5x amp vs 7x).
//   - lgcn_place: one block per 256-row bucket: LDS row-hist + block scan
//     produces row_ptr directly (bucket base = gbase[k][0]) and LDS cursors;
//     scatter to exact CSR position inside a ~40 KB single-XCD window.
//   Row-level hist/scan/cursor kernels and both memsets are deleted.
//
// Record packing: col (17 b) | row-within-bucket (8 b) << 17, val bits.
//
// ws layout (256 B aligned):
//   bufA : nd fp16 (x0, later x2)                 25.6 MB
//   bufB : nd fp16 (x1; int2 staging during build) 25.6 MB
//   edges: E int2                                  16 MB
//   row_ptr(n+1), ghist(512*256), gbase(+1), bsums ~1.5 MB

#define DIM 128
#define PB   256   // partition blocks
#define KPAD 512   // padded bucket count (nbuck = ceil(n/256) = 391 <= 512)
#define RPB  256   // rows per bucket

static inline size_t align_up(size_t v, size_t a) { return (v + a - 1) & ~(a - 1); }

__global__ void lgcn_conv(const float2* __restrict__ emb, __half2* __restrict__ x0,
                          int n2) {
    int i = blockIdx.x * blockDim.x + threadIdx.x;
    if (i < n2) x0[i] = __float22half2_rn(emb[i]);
}

// Per-block coarse histogram: block b owns edges [b*chunk, (b+1)*chunk).
__global__ void __launch_bounds__(256)
lgcn_phist(const int* __restrict__ rows, int* __restrict__ ghist, int nedges) {
    __shared__ int h[KPAD];
    const int b = blockIdx.x, tid = threadIdx.x;
    for (int k = tid; k < KPAD; k += 256) h[k] = 0;
    __syncthreads();
    const int chunk = (nedges + PB - 1) / PB;
    const int beg = b * chunk;
    const int end = min(beg + chunk, nedges);
    for (int e = beg + tid; e < end; e += 256)
        atomicAdd(&h[rows[e] >> 8], 1);
    __syncthreads();
    for (int k = tid; k < KPAD; k += 256) ghist[(k << 8) + b] = h[k];
}

// Level-1 scan: each 256-thread block scans 1024 counts (4/thread).
__global__ void __launch_bounds__(256)
lgcn_scan1(const int* __restrict__ counts, int* __restrict__ outp,
           int* __restrict__ bsums, int n) {
    __shared__ int wsum[4];
    const int tid  = threadIdx.x;
    const int lane = tid & 63;
    const int wid  = tid >> 6;
    const int i0   = blockIdx.x * 1024 + tid * 4;

    int c0 = 0, c1 = 0, c2 = 0, c3 = 0;
    if (i0 + 3 < n) {
        int4 c = *(const int4*)(counts + i0);
        c0 = c.x; c1 = c.y; c2 = c.z; c3 = c.w;
    } else {
        if (i0 + 0 < n) c0 = counts[i0 + 0];
        if (i0 + 1 < n) c1 = counts[i0 + 1];
        if (i0 + 2 < n) c2 = counts[i0 + 2];
        if (i0 + 3 < n) c3 = counts[i0 + 3];
    }
    const int t1 = c0 + c1, t2 = t1 + c2, tsum = t2 + c3;

    int incl = tsum;
    #pragma unroll
    for (int off = 1; off < 64; off <<= 1) {
        int t = __shfl_up(incl, off, 64);
        if (lane >= off) incl += t;
    }
    if (lane == 63) wsum[wid] = incl;
    __syncthreads();
    int woff = 0;
    #pragma unroll
    for (int w = 0; w < 4; ++w) woff += (w < wid) ? wsum[w] : 0;

    const int ex = woff + incl - tsum;
    if (i0 + 0 < n) outp[i0 + 0] = ex;
    if (i0 + 1 < n) outp[i0 + 1] = ex + c0;
    if (i0 + 2 < n) outp[i0 + 2] = ex + t1;
    if (i0 + 3 < n) outp[i0 + 3] = ex + t2;
    if (tid == 255) bsums[blockIdx.x] = woff + incl;
}

// Level-2: exclusive-scan the (<=128) block sums; write grand total to outp[n].
__global__ void __launch_bounds__(128)
lgcn_scan2(int* __restrict__ bsums, int* __restrict__ outp, int nb, int n) {
    __shared__ int w0s;
    const int tid  = threadIdx.x;
    const int lane = tid & 63;
    const int wid  = tid >> 6;
    int v = (tid < nb) ? bsums[tid] : 0;
    int incl = v;
    #pragma unroll
    for (int off = 1; off < 64; off <<= 1) {
        int t = __shfl_up(incl, off, 64);
        if (lane >= off) incl += t;
    }
    if (tid == 63) w0s = incl;
    __syncthreads();
    const int ex = incl - v + ((wid == 1) ? w0s : 0);
    if (tid < nb) bsums[tid] = ex;
    if (tid == nb - 1) outp[n] = ex + v;
}

// Level-3: add block bases.
__global__ void lgcn_scan3(int* __restrict__ outp, const int* __restrict__ bsums,
                           int n) {
    int i = blockIdx.x * blockDim.x + threadIdx.x;
    if (i < n) outp[i] += bsums[i >> 10];
}

// Deterministic partition: block b re-reads its chunk; LDS counters start at
// gbase[k][b]; each edge goes to a contiguous (block,bucket) range written by
// this CU only.
__global__ void __launch_bounds__(256)
lgcn_part(const int* __restrict__ rows, const int* __restrict__ cols,
          const float* __restrict__ vals, const int* __restrict__ gbase,
          int2* __restrict__ staging, int nedges) {
    __shared__ int lcnt[KPAD];
    const int b = blockIdx.x, tid = threadIdx.x;
    for (int k = tid; k < KPAD; k += 256) lcnt[k] = gbase[(k << 8) + b];
    __syncthreads();
    const int chunk = (nedges + PB - 1) / PB;
    const int beg = b * chunk;
    const int end = min(beg + chunk, nedges);
    for (int e = beg + tid; e < end; e += 256) {
        int r   = rows[e];
        int pos = atomicAdd(&lcnt[r >> 8], 1);
        staging[pos] = make_int2(cols[e] | ((r & 255) << 17), __float_as_int(vals[e]));
    }
}

// One block per 256-row bucket: LDS row-hist + block scan -> row_ptr and LDS
// cursors; scatter staging range to exact CSR slots (single-XCD ~40 KB window).
__global__ void __launch_bounds__(256)
lgcn_place(const int* __restrict__ gbase, const int2* __restrict__ staging,
           int* __restrict__ row_ptr, int2* __restrict__ edges, int n, int nbuck) {
    __shared__ int rcnt[RPB];
    __shared__ int cur[RPB];
    __shared__ int wsum[4];
    const int k    = blockIdx.x;
    const int tid  = threadIdx.x;
    const int lane = tid & 63;
    const int wid  = tid >> 6;
    const int base = gbase[k << 8];          // gbase[k][0]
    const int next = gbase[(k + 1) << 8];    // gbase[k+1][0]

    rcnt[tid] = 0;
    __syncthreads();
    for (int i = base + tid; i < next; i += 256)
        atomicAdd(&rcnt[(staging[i].x >> 17) & 255], 1);
    __syncthreads();

    // block-exclusive scan of the 256 row counts
    const int v = rcnt[tid];
    int incl = v;
    #pragma unroll
    for (int off = 1; off < 64; off <<= 1) {
        int t = __shfl_up(incl, off, 64);
        if (lane >= off) incl += t;
    }
    if (lane == 63) wsum[wid] = incl;
    __syncthreads();
    int woff = 0;
    #pragma unroll
    for (int w = 0; w < 4; ++w) woff += (w < wid) ? wsum[w] : 0;
    const int ex = woff + incl - v;

    cur[tid] = base + ex;
    const int r = (k << 8) + tid;
    if (r < n) row_ptr[r] = base + ex;
    if (k == nbuck - 1 && tid == 0) row_ptr[n] = next;
    __syncthreads();

    for (int i = base + tid; i < next; i += 256) {
        int2 p  = staging[i];
        int pos = atomicAdd(&cur[(p.x >> 17) & 255], 1);
        edges[pos] = make_int2(p.x & 0x1FFFF, p.y);
    }
}

// One wave per row; lane j holds dims [2j, 2j+1] (one __half2 = 4 B gather/lane).
// mode 0: xout[row] = fp16(s)
// mode 1: out[row]  = (emb[row] + x1[row] + xin[row](=x2) + s) * 0.25  (fp32)
__global__ void __launch_bounds__(256)
lgcn_spmm(const int* __restrict__ row_ptr, const int2* __restrict__ edges,
          const __half2* __restrict__ xin, __half2* __restrict__ xout,
          const float2* __restrict__ emb, const __half2* __restrict__ x1h,
          float2* __restrict__ out, int n, int mode) {
    const int wave = blockIdx.x * 4 + (threadIdx.x >> 6);
    const int lane = threadIdx.x & 63;
    if (wave >= n) return;
    const int beg = row_ptr[wave];
    const int end = row_ptr[wave + 1];

    float sx = 0.f, sy = 0.f;
    int e = beg;
    for (; e + 4 <= end; e += 4) {
        int2 p0 = edges[e + 0], p1 = edges[e + 1];
        int2 p2 = edges[e + 2], p3 = edges[e + 3];
        float2 a0 = __half22float2(xin[p0.x * 64 + lane]);
        float2 a1 = __half22float2(xin[p1.x * 64 + lane]);
        float2 a2 = __half22float2(xin[p2.x * 64 + lane]);
        float2 a3 = __half22float2(xin[p3.x * 64 + lane]);
        float v0 = __int_as_float(p0.y), v1 = __int_as_float(p1.y);
        float v2 = __int_as_float(p2.y), v3 = __int_as_float(p3.y);
        sx = fmaf(v0, a0.x, sx); sy = fmaf(v0, a0.y, sy);
        sx = fmaf(v1, a1.x, sx); sy = fmaf(v1, a1.y, sy);
        sx = fmaf(v2, a2.x, sx); sy = fmaf(v2, a2.y, sy);
        sx = fmaf(v3, a3.x, sx); sy = fmaf(v3, a3.y, sy);
    }
    for (; e < end; ++e) {
        int2 p = edges[e];
        float2 a = __half22float2(xin[p.x * 64 + lane]);
        float v  = __int_as_float(p.y);
        sx = fmaf(v, a.x, sx); sy = fmaf(v, a.y, sy);
    }

    const int o = wave * 64 + lane;
    if (mode == 0) {
        xout[o] = __float22half2_rn(make_float2(sx, sy));
    } else {
        float2 em = emb[o];
        float2 b1 = __half22float2(x1h[o]);
        float2 b2 = __half22float2(xin[o]);
        out[o] = make_float2((em.x + b1.x + b2.x + sx) * 0.25f,
                             (em.y + b1.y + b2.y + sy) * 0.25f);
    }
}

extern "C" void kernel_launch(void* const* d_in, const int* in_sizes, int n_in,
                              void* d_out, int out_size, void* d_ws, size_t ws_size,
                              hipStream_t stream) {
    const float* emb  = (const float*)d_in[0];
    const int*   rows = (const int*)d_in[1];
    const int*   cols = (const int*)d_in[2];
    const float* vals = (const float*)d_in[3];

    const int  n_nodes = in_sizes[0] / DIM;    // 100000
    const int  nedges  = in_sizes[1];          // 2000000
    const long nd      = (long)n_nodes * DIM;  // 12.8M

    char* ws = (char*)d_ws;
    size_t off = 0;
    __half2* bufA = (__half2*)(ws + off); off = align_up(off + nd * 2, 256);   // x0 then x2
    __half2* bufB = (__half2*)(ws + off); off = align_up(off + nd * 2, 256);   // x1 / staging
    int2* edges   = (int2*)(ws + off);    off = align_up(off + (size_t)nedges * 8, 256);
    int* row_ptr  = (int*)(ws + off);     off = align_up(off + (size_t)(n_nodes + 1) * 4, 256);
    int* ghist    = (int*)(ws + off);     off = align_up(off + (size_t)KPAD * PB * 4, 256);
    int* gbase    = (int*)(ws + off);     off = align_up(off + ((size_t)KPAD * PB + 1) * 4, 256);
    int* bsums    = (int*)(ws + off);     off = align_up(off + 1024, 256);
    float2* out   = (float2*)d_out;

    int2* staging = (int2*)bufB;  // bufB is dead until spmm layer 1

    const int BS = 256;
    const int n2      = (int)(nd / 2);
    const int grid_c  = (n2 + BS - 1) / BS;
    const int nbuck   = (n_nodes + RPB - 1) / RPB;        // 391 (<= KPAD)
    const int nscan   = KPAD * PB;                        // 131072
    const int nb      = nscan / 1024;                     // 128 (scan2 capacity)
    const int grid_s  = (n_nodes + 3) / 4;                // 4 rows per block

    // emb -> fp16 x0
    lgcn_conv<<<grid_c, BS, 0, stream>>>((const float2*)emb, bufA, n2);

    // CSR build: no global atomics, no memsets.
    lgcn_phist<<<PB, BS, 0, stream>>>(rows, ghist, nedges);
    lgcn_scan1<<<nb, BS, 0, stream>>>(ghist, gbase, bsums, nscan);
    lgcn_scan2<<<1, 128, 0, stream>>>(bsums, gbase, nb, nscan);
    lgcn_scan3<<<nscan / BS, BS, 0, stream>>>(gbase, bsums, nscan);
    lgcn_part<<<PB, BS, 0, stream>>>(rows, cols, vals, gbase, staging, nedges);
    lgcn_place<<<nbuck, BS, 0, stream>>>(gbase, staging, row_ptr, edges, n_nodes, nbuck);

    // 3 SpMM layers: x1 = A x0, x2 = A x1, out = (emb + x1 + x2 + A x2)/4
    lgcn_spmm<<<grid_s, BS, 0, stream>>>(row_ptr, edges, bufA, bufB,
                                         nullptr, nullptr, nullptr, n_nodes, 0);
    lgcn_spmm<<<grid_s, BS, 0, stream>>>(row_ptr, edges, bufB, bufA,
                                         nullptr, nullptr, nullptr, n_nodes, 0);
    lgcn_spmm<<<grid_s, BS, 0, stream>>>(row_ptr, edges, bufA, nullptr,
                                         (const float2*)emb, bufB, out, n_nodes, 1);
}

// Round 3
// 418.200 us; speedup vs baseline: 1.5189x; 1.0831x over previous
//
#include <hip/hip_runtime.h>
#include <hip/hip_fp16.h>

// LightGCN propagation on MI355X — round 6: wide-gather SpMM (4 edges/instr).
// N = 100000 nodes, D = 128, E = 2,000,000 edges, 3 layers.
//
// Round-5 counters: 3x lgcn_spmm @ 94.6 us = 63% of total. FETCH 279 MB is
// within 25% of the XCD-replication floor (8 XCDs x 25.6 MB x + 16 MB edges
// = 221 MB) -> locality is nearly exhausted. But rate is only 3.56 TB/s vs
// 6.3 streaming, with VALUBusy 32% -> request-engine bound: 1 gather instr
// (4 lines) + 1 desc load PER EDGE, ~16 lines in flight per wave.
//
// Round 6 SpMM: lane = 16*g + l (g = edge slot 0..3, l = dim quarter).
//   - one global_load_dwordx4 (16 B/lane) fetches FOUR rows = 16 lines;
//   - one desc load serves 4 edges;
//   - main loop steps 16 edges: 4 independent gathers = 64 lines in
//     flight/wave (4x round-5), 4x fewer VMEM instructions;
//   - epilogue: 4-way cross-group reduce via 2 shfl_xor per accumulator.
// Build pipeline (deterministic two-pass sort) unchanged from round 5.
//
// ws layout (256 B aligned):
//   bufA : nd fp16 (x0, later x2)                 25.6 MB
//   bufB : nd fp16 (x1; int2 staging during build) 25.6 MB
//   edges: E int2                                  16 MB
//   row_ptr(n+1), ghist(512*256), gbase(+1), bsums ~1.5 MB

#define DIM 128
#define PB   256   // partition blocks
#define KPAD 512   // padded bucket count (nbuck = ceil(n/256) = 391 <= 512)
#define RPB  256   // rows per bucket

static inline size_t align_up(size_t v, size_t a) { return (v + a - 1) & ~(a - 1); }

__global__ void lgcn_conv(const float2* __restrict__ emb, __half2* __restrict__ x0,
                          int n2) {
    int i = blockIdx.x * blockDim.x + threadIdx.x;
    if (i < n2) x0[i] = __float22half2_rn(emb[i]);
}

// Per-block coarse histogram: block b owns edges [b*chunk, (b+1)*chunk).
__global__ void __launch_bounds__(256)
lgcn_phist(const int* __restrict__ rows, int* __restrict__ ghist, int nedges) {
    __shared__ int h[KPAD];
    const int b = blockIdx.x, tid = threadIdx.x;
    for (int k = tid; k < KPAD; k += 256) h[k] = 0;
    __syncthreads();
    const int chunk = (nedges + PB - 1) / PB;
    const int beg = b * chunk;
    const int end = min(beg + chunk, nedges);
    for (int e = beg + tid; e < end; e += 256)
        atomicAdd(&h[rows[e] >> 8], 1);
    __syncthreads();
    for (int k = tid; k < KPAD; k += 256) ghist[(k << 8) + b] = h[k];
}

// Level-1 scan: each 256-thread block scans 1024 counts (4/thread).
__global__ void __launch_bounds__(256)
lgcn_scan1(const int* __restrict__ counts, int* __restrict__ outp,
           int* __restrict__ bsums, int n) {
    __shared__ int wsum[4];
    const int tid  = threadIdx.x;
    const int lane = tid & 63;
    const int wid  = tid >> 6;
    const int i0   = blockIdx.x * 1024 + tid * 4;

    int c0 = 0, c1 = 0, c2 = 0, c3 = 0;
    if (i0 + 3 < n) {
        int4 c = *(const int4*)(counts + i0);
        c0 = c.x; c1 = c.y; c2 = c.z; c3 = c.w;
    } else {
        if (i0 + 0 < n) c0 = counts[i0 + 0];
        if (i0 + 1 < n) c1 = counts[i0 + 1];
        if (i0 + 2 < n) c2 = counts[i0 + 2];
        if (i0 + 3 < n) c3 = counts[i0 + 3];
    }
    const int t1 = c0 + c1, t2 = t1 + c2, tsum = t2 + c3;

    int incl = tsum;
    #pragma unroll
    for (int off = 1; off < 64; off <<= 1) {
        int t = __shfl_up(incl, off, 64);
        if (lane >= off) incl += t;
    }
    if (lane == 63) wsum[wid] = incl;
    __syncthreads();
    int woff = 0;
    #pragma unroll
    for (int w = 0; w < 4; ++w) woff += (w < wid) ? wsum[w] : 0;

    const int ex = woff + incl - tsum;
    if (i0 + 0 < n) outp[i0 + 0] = ex;
    if (i0 + 1 < n) outp[i0 + 1] = ex + c0;
    if (i0 + 2 < n) outp[i0 + 2] = ex + t1;
    if (i0 + 3 < n) outp[i0 + 3] = ex + t2;
    if (tid == 255) bsums[blockIdx.x] = woff + incl;
}

// Level-2: exclusive-scan the (<=128) block sums; write grand total to outp[n].
__global__ void __launch_bounds__(128)
lgcn_scan2(int* __restrict__ bsums, int* __restrict__ outp, int nb, int n) {
    __shared__ int w0s;
    const int tid  = threadIdx.x;
    const int lane = tid & 63;
    const int wid  = tid >> 6;
    int v = (tid < nb) ? bsums[tid] : 0;
    int incl = v;
    #pragma unroll
    for (int off = 1; off < 64; off <<= 1) {
        int t = __shfl_up(incl, off, 64);
        if (lane >= off) incl += t;
    }
    if (tid == 63) w0s = incl;
    __syncthreads();
    const int ex = incl - v + ((wid == 1) ? w0s : 0);
    if (tid < nb) bsums[tid] = ex;
    if (tid == nb - 1) outp[n] = ex + v;
}

// Level-3: add block bases.
__global__ void lgcn_scan3(int* __restrict__ outp, const int* __restrict__ bsums,
                           int n) {
    int i = blockIdx.x * blockDim.x + threadIdx.x;
    if (i < n) outp[i] += bsums[i >> 10];
}

// Deterministic partition: block b re-reads its chunk; LDS counters start at
// gbase[k][b]; each edge goes to a contiguous (block,bucket) range written by
// this CU only.
__global__ void __launch_bounds__(256)
lgcn_part(const int* __restrict__ rows, const int* __restrict__ cols,
          const float* __restrict__ vals, const int* __restrict__ gbase,
          int2* __restrict__ staging, int nedges) {
    __shared__ int lcnt[KPAD];
    const int b = blockIdx.x, tid = threadIdx.x;
    for (int k = tid; k < KPAD; k += 256) lcnt[k] = gbase[(k << 8) + b];
    __syncthreads();
    const int chunk = (nedges + PB - 1) / PB;
    const int beg = b * chunk;
    const int end = min(beg + chunk, nedges);
    for (int e = beg + tid; e < end; e += 256) {
        int r   = rows[e];
        int pos = atomicAdd(&lcnt[r >> 8], 1);
        staging[pos] = make_int2(cols[e] | ((r & 255) << 17), __float_as_int(vals[e]));
    }
}

// One block per 256-row bucket: LDS row-hist + block scan -> row_ptr and LDS
// cursors; scatter staging range to exact CSR slots (single-XCD ~40 KB window).
__global__ void __launch_bounds__(256)
lgcn_place(const int* __restrict__ gbase, const int2* __restrict__ staging,
           int* __restrict__ row_ptr, int2* __restrict__ edges, int n, int nbuck) {
    __shared__ int rcnt[RPB];
    __shared__ int cur[RPB];
    __shared__ int wsum[4];
    const int k    = blockIdx.x;
    const int tid  = threadIdx.x;
    const int lane = tid & 63;
    const int wid  = tid >> 6;
    const int base = gbase[k << 8];          // gbase[k][0]
    const int next = gbase[(k + 1) << 8];    // gbase[k+1][0]

    rcnt[tid] = 0;
    __syncthreads();
    for (int i = base + tid; i < next; i += 256)
        atomicAdd(&rcnt[(staging[i].x >> 17) & 255], 1);
    __syncthreads();

    // block-exclusive scan of the 256 row counts
    const int v = rcnt[tid];
    int incl = v;
    #pragma unroll
    for (int off = 1; off < 64; off <<= 1) {
        int t = __shfl_up(incl, off, 64);
        if (lane >= off) incl += t;
    }
    if (lane == 63) wsum[wid] = incl;
    __syncthreads();
    int woff = 0;
    #pragma unroll
    for (int w = 0; w < 4; ++w) woff += (w < wid) ? wsum[w] : 0;
    const int ex = woff + incl - v;

    cur[tid] = base + ex;
    const int r = (k << 8) + tid;
    if (r < n) row_ptr[r] = base + ex;
    if (k == nbuck - 1 && tid == 0) row_ptr[n] = next;
    __syncthreads();

    for (int i = base + tid; i < next; i += 256) {
        int2 p  = staging[i];
        int pos = atomicAdd(&cur[(p.x >> 17) & 255], 1);
        edges[pos] = make_int2(p.x & 0x1FFFF, p.y);
    }
}

// Wide-gather SpMM. One wave per row. lane = 16*g + l:
//   g = lane>>4 : edge slot (4 edges processed per gather instruction)
//   l = lane&15 : dim quarter, dims [8l, 8l+8) as one int4 of 8 fp16.
// Each slot accumulates its edges into acc[8] (fp32); epilogue reduces
// across the 4 slots with shfl_xor(16/32).
// mode 0: xout[row] = fp16(s)
// mode 1: out[row]  = (emb[row] + x1[row] + x2[row] + s) * 0.25  (fp32)
__global__ void __launch_bounds__(256)
lgcn_spmm(const int* __restrict__ row_ptr, const int2* __restrict__ edges,
          const __half2* __restrict__ xin, __half2* __restrict__ xout,
          const float2* __restrict__ emb, const __half2* __restrict__ x1h,
          float2* __restrict__ out, int n, int mode) {
    const int wave = blockIdx.x * 4 + (threadIdx.x >> 6);
    const int lane = threadIdx.x & 63;
    const int g    = lane >> 4;
    const int l    = lane & 15;
    if (wave >= n) return;
    const int beg = row_ptr[wave];
    const int end = row_ptr[wave + 1];

    const int4* __restrict__ x4 = (const int4*)xin;  // 16 int4 per row

    float a0 = 0.f, a1 = 0.f, a2 = 0.f, a3 = 0.f;
    float a4 = 0.f, a5 = 0.f, a6 = 0.f, a7 = 0.f;

#define FMA8(Q, V)                                                        \
    {                                                                     \
        float2 f0 = __half22float2(*(const __half2*)&(Q).x);              \
        float2 f1 = __half22float2(*(const __half2*)&(Q).y);              \
        float2 f2 = __half22float2(*(const __half2*)&(Q).z);              \
        float2 f3 = __half22float2(*(const __half2*)&(Q).w);              \
        a0 = fmaf((V), f0.x, a0); a1 = fmaf((V), f0.y, a1);               \
        a2 = fmaf((V), f1.x, a2); a3 = fmaf((V), f1.y, a3);               \
        a4 = fmaf((V), f2.x, a4); a5 = fmaf((V), f2.y, a5);               \
        a6 = fmaf((V), f3.x, a6); a7 = fmaf((V), f3.y, a7);               \
    }

    int e = beg;
    // main: 16 edges per iteration = 4 independent wide gathers (64 lines).
    for (; e + 16 <= end; e += 16) {
        int2 d0 = edges[e + g];
        int2 d1 = edges[e + 4 + g];
        int2 d2 = edges[e + 8 + g];
        int2 d3 = edges[e + 12 + g];
        int4 q0 = x4[d0.x * 16 + l];
        int4 q1 = x4[d1.x * 16 + l];
        int4 q2 = x4[d2.x * 16 + l];
        int4 q3 = x4[d3.x * 16 + l];
        FMA8(q0, __int_as_float(d0.y));
        FMA8(q1, __int_as_float(d1.y));
        FMA8(q2, __int_as_float(d2.y));
        FMA8(q3, __int_as_float(d3.y));
    }
    // mid tail: 8 edges.
    for (; e + 8 <= end; e += 8) {
        int2 d0 = edges[e + g];
        int2 d1 = edges[e + 4 + g];
        int4 q0 = x4[d0.x * 16 + l];
        int4 q1 = x4[d1.x * 16 + l];
        FMA8(q0, __int_as_float(d0.y));
        FMA8(q1, __int_as_float(d1.y));
    }
    // masked tail: up to 4 edges per iteration; masked lanes gather row 0
    // (hot line) with v = 0 -> no contribution.
    for (; e < end; e += 4) {
        const int ee = e + g;
        int2 d = (ee < end) ? edges[ee] : make_int2(0, 0);
        int4 q = x4[d.x * 16 + l];
        FMA8(q, __int_as_float(d.y));
    }
#undef FMA8

    // reduce across the 4 edge slots (groups differ in lane bits 4,5)
    a0 += __shfl_xor(a0, 16); a0 += __shfl_xor(a0, 32);
    a1 += __shfl_xor(a1, 16); a1 += __shfl_xor(a1, 32);
    a2 += __shfl_xor(a2, 16); a2 += __shfl_xor(a2, 32);
    a3 += __shfl_xor(a3, 16); a3 += __shfl_xor(a3, 32);
    a4 += __shfl_xor(a4, 16); a4 += __shfl_xor(a4, 32);
    a5 += __shfl_xor(a5, 16); a5 += __shfl_xor(a5, 32);
    a6 += __shfl_xor(a6, 16); a6 += __shfl_xor(a6, 32);
    a7 += __shfl_xor(a7, 16); a7 += __shfl_xor(a7, 32);

    if (mode == 0) {
        if (g == 0) {
            int4 r;
            __half2 h0 = __float22half2_rn(make_float2(a0, a1));
            __half2 h1 = __float22half2_rn(make_float2(a2, a3));
            __half2 h2 = __float22half2_rn(make_float2(a4, a5));
            __half2 h3 = __float22half2_rn(make_float2(a6, a7));
            r.x = *(const int*)&h0; r.y = *(const int*)&h1;
            r.z = *(const int*)&h2; r.w = *(const int*)&h3;
            ((int4*)xout)[wave * 16 + l] = r;
        }
    } else {
        // all groups compute redundantly (same lines, coalescer dedups);
        // only group 0 stores.
        float4 e0 = ((const float4*)emb)[wave * 32 + l * 2 + 0];
        float4 e1 = ((const float4*)emb)[wave * 32 + l * 2 + 1];
        int4  h1q = ((const int4*)x1h)[wave * 16 + l];
        int4  h2q = ((const int4*)xin)[wave * 16 + l];
        float2 b0 = __half22float2(*(const __half2*)&h1q.x);
        float2 b1 = __half22float2(*(const __half2*)&h1q.y);
        float2 b2 = __half22float2(*(const __half2*)&h1q.z);
        float2 b3 = __half22float2(*(const __half2*)&h1q.w);
        float2 c0 = __half22float2(*(const __half2*)&h2q.x);
        float2 c1 = __half22float2(*(const __half2*)&h2q.y);
        float2 c2 = __half22float2(*(const __half2*)&h2q.z);
        float2 c3 = __half22float2(*(const __half2*)&h2q.w);
        if (g == 0) {
            float4 r0, r1;
            r0.x = (e0.x + b0.x + c0.x + a0) * 0.25f;
            r0.y = (e0.y + b0.y + c0.y + a1) * 0.25f;
            r0.z = (e0.z + b1.x + c1.x + a2) * 0.25f;
            r0.w = (e0.w + b1.y + c1.y + a3) * 0.25f;
            r1.x = (e1.x + b2.x + c2.x + a4) * 0.25f;
            r1.y = (e1.y + b2.y + c2.y + a5) * 0.25f;
            r1.z = (e1.z + b3.x + c3.x + a6) * 0.25f;
            r1.w = (e1.w + b3.y + c3.y + a7) * 0.25f;
            ((float4*)out)[wave * 32 + l * 2 + 0] = r0;
            ((float4*)out)[wave * 32 + l * 2 + 1] = r1;
        }
    }
}

extern "C" void kernel_launch(void* const* d_in, const int* in_sizes, int n_in,
                              void* d_out, int out_size, void* d_ws, size_t ws_size,
                              hipStream_t stream) {
    const float* emb  = (const float*)d_in[0];
    const int*   rows = (const int*)d_in[1];
    const int*   cols = (const int*)d_in[2];
    const float* vals = (const float*)d_in[3];

    const int  n_nodes = in_sizes[0] / DIM;    // 100000
    const int  nedges  = in_sizes[1];          // 2000000
    const long nd      = (long)n_nodes * DIM;  // 12.8M

    char* ws = (char*)d_ws;
    size_t off = 0;
    __half2* bufA = (__half2*)(ws + off); off = align_up(off + nd * 2, 256);   // x0 then x2
    __half2* bufB = (__half2*)(ws + off); off = align_up(off + nd * 2, 256);   // x1 / staging
    int2* edges   = (int2*)(ws + off);    off = align_up(off + (size_t)nedges * 8, 256);
    int* row_ptr  = (int*)(ws + off);     off = align_up(off + (size_t)(n_nodes + 1) * 4, 256);
    int* ghist    = (int*)(ws + off);     off = align_up(off + (size_t)KPAD * PB * 4, 256);
    int* gbase    = (int*)(ws + off);     off = align_up(off + ((size_t)KPAD * PB + 1) * 4, 256);
    int* bsums    = (int*)(ws + off);     off = align_up(off + 1024, 256);
    float2* out   = (float2*)d_out;

    int2* staging = (int2*)bufB;  // bufB is dead until spmm layer 1

    const int BS = 256;
    const int n2      = (int)(nd / 2);
    const int grid_c  = (n2 + BS - 1) / BS;
    const int nbuck   = (n_nodes + RPB - 1) / RPB;        // 391 (<= KPAD)
    const int nscan   = KPAD * PB;                        // 131072
    const int nb      = nscan / 1024;                     // 128 (scan2 capacity)
    const int grid_s  = (n_nodes + 3) / 4;                // 4 rows per block

    // emb -> fp16 x0
    lgcn_conv<<<grid_c, BS, 0, stream>>>((const float2*)emb, bufA, n2);

    // CSR build: no global atomics, no memsets.
    lgcn_phist<<<PB, BS, 0, stream>>>(rows, ghist, nedges);
    lgcn_scan1<<<nb, BS, 0, stream>>>(ghist, gbase, bsums, nscan);
    lgcn_scan2<<<1, 128, 0, stream>>>(bsums, gbase, nb, nscan);
    lgcn_scan3<<<nscan / BS, BS, 0, stream>>>(gbase, bsums, nscan);
    lgcn_part<<<PB, BS, 0, stream>>>(rows, cols, vals, gbase, staging, nedges);
    lgcn_place<<<nbuck, BS, 0, stream>>>(gbase, staging, row_ptr, edges, n_nodes, nbuck);

    // 3 SpMM layers: x1 = A x0, x2 = A x1, out = (emb + x1 + x2 + A x2)/4
    lgcn_spmm<<<grid_s, BS, 0, stream>>>(row_ptr, edges, bufA, bufB,
                                         nullptr, nullptr, nullptr, n_nodes, 0);
    lgcn_spmm<<<grid_s, BS, 0, stream>>>(row_ptr, edges, bufB, bufA,
                                         nullptr, nullptr, nullptr, n_nodes, 0);
    lgcn_spmm<<<grid_s, BS, 0, stream>>>(row_ptr, edges, bufA, nullptr,
                                         (const float2*)emb, bufB, out, n_nodes, 1);
}